// Round 1
// baseline (239.527 us; speedup 1.0000x reference)
//
#include <hip/hip_runtime.h>

typedef unsigned long long u64;

#define NB 64
#define NQ 900
#define NCLS 81     // C+1
#define NVERB 117
#define NBQ (NB*NQ)
#define NWORD 15    // ceil(900/64)
#define WSTRIDE 16  // padded words per cand row

// ---------------- Kernel A: per-(b,q) scores/labels/boxes, one wave each ----
__global__ __launch_bounds__(256) void kA(
    const float* __restrict__ obj_logits, const float* __restrict__ verb_logits,
    const float* __restrict__ sub_boxes, const float* __restrict__ obj_boxes,
    const int* __restrict__ target_sizes, const float* __restrict__ cmat,
    float* __restrict__ out_hoi, float* __restrict__ out_lab,
    float* __restrict__ out_sb, float* __restrict__ out_ob,
    float* __restrict__ ws_max, int* __restrict__ ws_lab)
{
    int wid  = (blockIdx.x * blockDim.x + threadIdx.x) >> 6;
    int lane = threadIdx.x & 63;
    if (wid >= NBQ) return;
    int b = wid / NQ;

    // max + argmax over 81 logits (first-index tie-break)
    const float* ol = obj_logits + (size_t)wid * NCLS;
    float m  = ol[lane];
    int   mi = lane;
    if (lane < NCLS - 64) {
        float v1 = ol[64 + lane];
        if (v1 > m) { m = v1; mi = 64 + lane; }   // strict >: keeps smaller index
    }
    for (int off = 32; off; off >>= 1) {
        float om  = __shfl_xor(m, off);
        int   omi = __shfl_xor(mi, off);
        if (om > m || (om == m && omi < mi)) { m = om; mi = omi; }
    }
    float obj_score = 1.0f / (1.0f + expf(-m));
    if (lane == 0) { out_lab[wid] = (float)mi; ws_lab[wid] = mi; }

    // verb sigmoids * obj_score * mask; row max
    const float* vl = verb_logits + (size_t)wid * NVERB;
    float* oh = out_hoi + (size_t)wid * NVERB;
    float mx = -1.0f;                       // all hoi scores >= 0
    for (int v = lane; v < NVERB; v += 64) {
        float s = 1.0f / (1.0f + expf(-vl[v]));
        float msk = (mi < NCLS - 1) ? cmat[v * (NCLS - 1) + mi] : 1.0f;
        float h = s * obj_score * msk;
        oh[v] = h;
        mx = fmaxf(mx, h);
    }
    for (int off = 32; off; off >>= 1) mx = fmaxf(mx, __shfl_xor(mx, off));
    if (lane == 0) ws_max[wid] = mx;

    // scaled xyxy boxes (lane 0: subject, lane 1: object)
    if (lane < 2) {
        const float* bx = (lane == 0 ? sub_boxes : obj_boxes) + (size_t)wid * 4;
        float* o = (lane == 0 ? out_sb : out_ob) + (size_t)wid * 4;
        float cx = bx[0], cy = bx[1], w = bx[2], h = bx[3];
        float ih = (float)target_sizes[b * 2 + 0];
        float iw = (float)target_sizes[b * 2 + 1];
        o[0] = (cx - 0.5f * w) * iw;
        o[1] = (cy - 0.5f * h) * ih;
        o[2] = (cx + 0.5f * w) * iw;
        o[3] = (cy + 0.5f * h) * ih;
    }
}

// ---------------- Kernel B: per-batch stable descending sort by rank -------
__global__ __launch_bounds__(256) void kB(
    const float* __restrict__ ws_max, const int* __restrict__ ws_lab,
    const float* __restrict__ out_sb, const float* __restrict__ out_ob,
    int* __restrict__ ws_ord,
    float* __restrict__ sx1, float* __restrict__ sy1, float* __restrict__ sx2,
    float* __restrict__ sy2, float* __restrict__ sar,
    float* __restrict__ ox1, float* __restrict__ oy1, float* __restrict__ ox2,
    float* __restrict__ oy2, float* __restrict__ oar,
    int* __restrict__ slab)
{
    __shared__ float sc[NQ];
    int b = blockIdx.x, t = threadIdx.x;
    for (int i = t; i < NQ; i += 256) sc[i] = ws_max[b * NQ + i];
    __syncthreads();
    for (int q = t; q < NQ; q += 256) {
        float sq = sc[q];
        int rank = 0;
        for (int j = 0; j < NQ; ++j) {
            float sj = sc[j];
            rank += (sj > sq) || (sj == sq && j < q);
        }
        int src = b * NQ + q, dst = b * NQ + rank;
        ws_ord[dst] = q;
        float x1 = out_sb[src * 4 + 0], y1 = out_sb[src * 4 + 1];
        float x2 = out_sb[src * 4 + 2], y2 = out_sb[src * 4 + 3];
        sx1[dst] = x1; sy1[dst] = y1; sx2[dst] = x2; sy2[dst] = y2;
        sar[dst] = (x2 - x1 + 1.0f) * (y2 - y1 + 1.0f);
        x1 = out_ob[src * 4 + 0]; y1 = out_ob[src * 4 + 1];
        x2 = out_ob[src * 4 + 2]; y2 = out_ob[src * 4 + 3];
        ox1[dst] = x1; oy1[dst] = y1; ox2[dst] = x2; oy2[dst] = y2;
        oar[dst] = (x2 - x1 + 1.0f) * (y2 - y1 + 1.0f);
        slab[dst] = ws_lab[src];
    }
}

// ---------------- Kernel C: cand bitmask, one wave per sorted row ----------
__global__ __launch_bounds__(256) void kC(
    const float* __restrict__ sx1, const float* __restrict__ sy1,
    const float* __restrict__ sx2, const float* __restrict__ sy2,
    const float* __restrict__ sar,
    const float* __restrict__ ox1, const float* __restrict__ oy1,
    const float* __restrict__ ox2, const float* __restrict__ oy2,
    const float* __restrict__ oar,
    const int* __restrict__ slab, u64* __restrict__ cand)
{
    int wid  = (blockIdx.x * blockDim.x + threadIdx.x) >> 6;
    int lane = threadIdx.x & 63;
    if (wid >= NBQ) return;
    int b = wid / NQ, i = wid - b * NQ;
    int base = b * NQ;

    float xs1i = sx1[base + i], ys1i = sy1[base + i];
    float xs2i = sx2[base + i], ys2i = sy2[base + i], sari = sar[base + i];
    float xo1i = ox1[base + i], yo1i = oy1[base + i];
    float xo2i = ox2[base + i], yo2i = oy2[base + i], oari = oar[base + i];
    int li = slab[base + i];

    u64* crow = cand + (size_t)wid * WSTRIDE;
    int w0 = i >> 6;
    if (lane < w0) crow[lane] = 0ull;   // zero lower-triangle words
    for (int wj = w0; wj < NWORD; ++wj) {
        int j = wj * 64 + lane;
        bool pred = false;
        if (j > i && j < NQ) {
            int jj = base + j;
            if (slab[jj] == li) {
                float xx1 = fmaxf(xs1i, sx1[jj]);
                float yy1 = fmaxf(ys1i, sy1[jj]);
                float xx2 = fminf(xs2i, sx2[jj]);
                float yy2 = fminf(ys2i, sy2[jj]);
                float w = fmaxf(0.0f, xx2 - xx1 + 1.0f);
                float h = fmaxf(0.0f, yy2 - yy1 + 1.0f);
                float inter = w * h;
                float iouS = inter / (sari + sar[jj] - inter);
                xx1 = fmaxf(xo1i, ox1[jj]);
                yy1 = fmaxf(yo1i, oy1[jj]);
                xx2 = fminf(xo2i, ox2[jj]);
                yy2 = fminf(yo2i, oy2[jj]);
                w = fmaxf(0.0f, xx2 - xx1 + 1.0f);
                h = fmaxf(0.0f, yy2 - yy1 + 1.0f);
                float interO = w * h;
                float iouO = interO / (oari + oar[jj] - interO);
                float ovr = iouS * sqrtf(iouO);
                pred = ovr > 0.7f;
            }
        }
        u64 bal = __ballot((int)pred);
        if (lane == 0) crow[wj] = bal;
    }
}

// ---------------- Kernel D: greedy sequential scan, one block per batch ----
#define CHUNK 64
__global__ __launch_bounds__(256) void kD(
    const u64* __restrict__ cand, const int* __restrict__ ws_ord,
    float* __restrict__ out_keep)
{
    __shared__ u64  cl[2][CHUNK * WSTRIDE];   // 16 KB double buffer
    __shared__ int   ord[NQ];
    __shared__ float kf[NQ];
    int b = blockIdx.x, t = threadIdx.x;
    int lane = t & 63, wv = t >> 6;
    const u64* src = cand + (size_t)b * NQ * WSTRIDE;

    for (int k = t; k < CHUNK * WSTRIDE; k += 256) cl[0][k] = src[k];
    for (int k = t; k < NQ; k += 256) ord[k] = ws_ord[b * NQ + k];
    __syncthreads();

    const int nch = (NQ + CHUNK - 1) / CHUNK;   // 15
    u64 remv = 0ull;
    for (int ch = 0; ch < nch; ++ch) {
        // waves 1..3: prefetch next chunk
        if (wv > 0 && ch + 1 < nch) {
            int gbase = (ch + 1) * CHUNK * WSTRIDE;
            int cnt = min(CHUNK, NQ - (ch + 1) * CHUNK) * WSTRIDE;
            for (int k = t - 64; k < cnt; k += 192)
                cl[(ch + 1) & 1][k] = src[gbase + k];
        }
        // wave 0: sequential greedy over this chunk
        if (wv == 0) {
            int rows = min(CHUNK, NQ - ch * CHUNK);
            const u64* C = cl[ch & 1];
            for (int r = 0; r < rows; ++r) {
                int i = ch * CHUNK + r;
                int wi = i >> 6, bi = i & 63;
                int sup = __any((int)((lane == wi) && ((remv >> bi) & 1ull)));
                u64 c = C[r * WSTRIDE + (lane & 15)];
                u64 msk = (!sup && lane < NWORD) ? ~0ull : 0ull;
                remv |= (c & msk);
                if (lane == 0) kf[i] = sup ? 0.0f : 1.0f;
            }
        }
        __syncthreads();
    }
    for (int k = t; k < NQ; k += 256) out_keep[b * NQ + ord[k]] = kf[k];
}

extern "C" void kernel_launch(void* const* d_in, const int* in_sizes, int n_in,
                              void* d_out, int out_size, void* d_ws, size_t ws_size,
                              hipStream_t stream)
{
    const float* obj_logits   = (const float*)d_in[0];
    const float* verb_logits  = (const float*)d_in[1];
    const float* sub_boxes    = (const float*)d_in[2];
    const float* obj_boxes    = (const float*)d_in[3];
    const int*   target_sizes = (const int*)d_in[4];
    const float* cmat         = (const float*)d_in[5];

    float* out      = (float*)d_out;
    float* out_hoi  = out;
    float* out_lab  = out_hoi + (size_t)NBQ * NVERB;
    float* out_sb   = out_lab + NBQ;
    float* out_ob   = out_sb + (size_t)NBQ * 4;
    float* out_keep = out_ob + (size_t)NBQ * 4;

    float* ws_max = (float*)d_ws;
    int*   ws_lab = (int*)(ws_max + NBQ);
    int*   ws_ord = ws_lab + NBQ;
    float* sx1 = (float*)(ws_ord + NBQ);
    float* sy1 = sx1 + NBQ; float* sx2 = sy1 + NBQ; float* sy2 = sx2 + NBQ;
    float* sar = sy2 + NBQ;
    float* ox1 = sar + NBQ; float* oy1 = ox1 + NBQ; float* ox2 = oy1 + NBQ;
    float* oy2 = ox2 + NBQ; float* oar = oy2 + NBQ;
    int*   slab = (int*)(oar + NBQ);
    u64*   cand = (u64*)(slab + NBQ);   // byte offset 3,225,600 (8B aligned)

    kA<<<NBQ / 4, 256, 0, stream>>>(obj_logits, verb_logits, sub_boxes, obj_boxes,
                                    target_sizes, cmat,
                                    out_hoi, out_lab, out_sb, out_ob, ws_max, ws_lab);
    kB<<<NB, 256, 0, stream>>>(ws_max, ws_lab, out_sb, out_ob, ws_ord,
                               sx1, sy1, sx2, sy2, sar,
                               ox1, oy1, ox2, oy2, oar, slab);
    kC<<<NBQ / 4, 256, 0, stream>>>(sx1, sy1, sx2, sy2, sar,
                                    ox1, oy1, ox2, oy2, oar, slab, cand);
    kD<<<NB, 256, 0, stream>>>(cand, ws_ord, out_keep);
}

// Round 2
// 205.833 us; speedup vs baseline: 1.1637x; 1.1637x over previous
//
#include <hip/hip_runtime.h>

typedef unsigned long long u64;

#define NB 64
#define NQ 900
#define NCLS 81     // C+1
#define NVERB 117
#define NBQ (NB*NQ)
#define NWORD 15    // ceil(900/64)
#define WSTRIDE 16  // padded words per cand row

// ---------------- Kernel A: per-(b,q) scores/labels/boxes, one wave each ----
__global__ __launch_bounds__(256) void kA(
    const float* __restrict__ obj_logits, const float* __restrict__ verb_logits,
    const float* __restrict__ sub_boxes, const float* __restrict__ obj_boxes,
    const int* __restrict__ target_sizes, const float* __restrict__ cmat,
    float* __restrict__ out_hoi, float* __restrict__ out_lab,
    float* __restrict__ out_sb, float* __restrict__ out_ob,
    float* __restrict__ ws_max, int* __restrict__ ws_lab)
{
    int wid  = (blockIdx.x * blockDim.x + threadIdx.x) >> 6;
    int lane = threadIdx.x & 63;
    if (wid >= NBQ) return;
    int b = wid / NQ;

    // max + argmax over 81 logits (first-index tie-break)
    const float* ol = obj_logits + (size_t)wid * NCLS;
    float m  = ol[lane];
    int   mi = lane;
    if (lane < NCLS - 64) {
        float v1 = ol[64 + lane];
        if (v1 > m) { m = v1; mi = 64 + lane; }   // strict >: keeps smaller index
    }
    for (int off = 32; off; off >>= 1) {
        float om  = __shfl_xor(m, off);
        int   omi = __shfl_xor(mi, off);
        if (om > m || (om == m && omi < mi)) { m = om; mi = omi; }
    }
    float obj_score = 1.0f / (1.0f + expf(-m));
    if (lane == 0) { out_lab[wid] = (float)mi; ws_lab[wid] = mi; }

    // verb sigmoids * obj_score * mask; row max
    const float* vl = verb_logits + (size_t)wid * NVERB;
    float* oh = out_hoi + (size_t)wid * NVERB;
    float mx = -1.0f;                       // all hoi scores >= 0
    for (int v = lane; v < NVERB; v += 64) {
        float s = 1.0f / (1.0f + expf(-vl[v]));
        float msk = (mi < NCLS - 1) ? cmat[v * (NCLS - 1) + mi] : 1.0f;
        float h = s * obj_score * msk;
        oh[v] = h;
        mx = fmaxf(mx, h);
    }
    for (int off = 32; off; off >>= 1) mx = fmaxf(mx, __shfl_xor(mx, off));
    if (lane == 0) ws_max[wid] = mx;

    // scaled xyxy boxes (lane 0: subject, lane 1: object)
    if (lane < 2) {
        const float* bx = (lane == 0 ? sub_boxes : obj_boxes) + (size_t)wid * 4;
        float* o = (lane == 0 ? out_sb : out_ob) + (size_t)wid * 4;
        float cx = bx[0], cy = bx[1], w = bx[2], h = bx[3];
        float ih = (float)target_sizes[b * 2 + 0];
        float iw = (float)target_sizes[b * 2 + 1];
        o[0] = (cx - 0.5f * w) * iw;
        o[1] = (cy - 0.5f * h) * ih;
        o[2] = (cx + 0.5f * w) * iw;
        o[3] = (cy + 0.5f * h) * ih;
    }
}

// ------------- Kernel B: rank-by-count sort, grid=(4 q-chunks, NB) ---------
__global__ __launch_bounds__(256) void kB(
    const float* __restrict__ ws_max, const int* __restrict__ ws_lab,
    const float* __restrict__ out_sb, const float* __restrict__ out_ob,
    int* __restrict__ ws_ord,
    float4* __restrict__ sbox4, float4* __restrict__ obox4,
    float* __restrict__ sar, float* __restrict__ oar,
    int* __restrict__ slab)
{
    __shared__ float sc[NQ];
    int b = blockIdx.y, t = threadIdx.x;
    for (int i = t; i < NQ; i += 256) sc[i] = ws_max[b * NQ + i];
    __syncthreads();
    int q = blockIdx.x * 256 + t;
    if (q >= NQ) return;
    float sq = sc[q];
    int rank = 0;
    #pragma unroll 4
    for (int j = 0; j < NQ; ++j) {
        float sj = sc[j];
        rank += (sj > sq) || (sj == sq && j < q);
    }
    int src = b * NQ + q, dst = b * NQ + rank;
    ws_ord[dst] = q;
    float4 s4 = *reinterpret_cast<const float4*>(out_sb + (size_t)src * 4);
    float4 o4 = *reinterpret_cast<const float4*>(out_ob + (size_t)src * 4);
    sbox4[dst] = s4;
    obox4[dst] = o4;
    sar[dst] = (s4.z - s4.x + 1.0f) * (s4.w - s4.y + 1.0f);
    oar[dst] = (o4.z - o4.x + 1.0f) * (o4.w - o4.y + 1.0f);
    slab[dst] = ws_lab[src];
}

// ------- Kernel C: cand bitmask, LDS-staged batch, grid=(15 chunks, NB) ----
__global__ __launch_bounds__(256) void kC(
    const float4* __restrict__ sbox4, const float4* __restrict__ obox4,
    const float* __restrict__ sar, const float* __restrict__ oar,
    const int* __restrict__ slab, u64* __restrict__ cand)
{
    __shared__ float4 Lsb[NQ];
    __shared__ float4 Lob[NQ];
    __shared__ float  Lsa[NQ];
    __shared__ float  Loa[NQ];
    __shared__ int    Llab[NQ];
    int b = blockIdx.y, t = threadIdx.x;
    int base = b * NQ;
    for (int k = t; k < NQ; k += 256) {
        Lsb[k] = sbox4[base + k];
        Lob[k] = obox4[base + k];
        Lsa[k] = sar[base + k];
        Loa[k] = oar[base + k];
        Llab[k] = slab[base + k];
    }
    __syncthreads();

    int lane = t & 63, wv = t >> 6;
    for (int r = wv; r < 60; r += 4) {
        int i = blockIdx.x * 60 + r;
        float4 si = Lsb[i]; float sari = Lsa[i];
        float4 oi = Lob[i]; float oari = Loa[i];
        int li = Llab[i];
        u64* crow = cand + ((size_t)base + i) * WSTRIDE;
        int w0 = i >> 6;
        if (lane < w0) crow[lane] = 0ull;   // zero lower-triangle words
        for (int wj = w0; wj < NWORD; ++wj) {
            int j = wj * 64 + lane;
            int jc = j < NQ ? j : NQ - 1;
            bool cl = (j > i) && (j < NQ) && (Llab[jc] == li);
            u64 bal = 0ull;
            if (__any((int)cl)) {
                float4 sj = Lsb[jc];
                float4 oj = Lob[jc];
                float xx1 = fmaxf(si.x, sj.x), yy1 = fmaxf(si.y, sj.y);
                float xx2 = fminf(si.z, sj.z), yy2 = fminf(si.w, sj.w);
                float w = fmaxf(0.0f, xx2 - xx1 + 1.0f);
                float h = fmaxf(0.0f, yy2 - yy1 + 1.0f);
                float iS = w * h;
                float uS = sari + Lsa[jc] - iS;
                xx1 = fmaxf(oi.x, oj.x); yy1 = fmaxf(oi.y, oj.y);
                xx2 = fminf(oi.z, oj.z); yy2 = fminf(oi.w, oj.w);
                w = fmaxf(0.0f, xx2 - xx1 + 1.0f);
                h = fmaxf(0.0f, yy2 - yy1 + 1.0f);
                float iO = w * h;
                float uO = oari + Loa[jc] - iO;
                // iouS * sqrt(iouO) > 0.7  <=>  iS^2*iO > 0.49*uS^2*uO  (all >= 0, unions >= 1)
                bool pred = cl && (iS * iS * iO > 0.49f * uS * uS * uO);
                bal = __ballot((int)pred);
            }
            if (lane == 0) crow[wj] = bal;
        }
    }
}

// ---------------- Kernel D: greedy sequential scan, one block per batch ----
#define CHUNK 64
__global__ __launch_bounds__(256) void kD(
    const u64* __restrict__ cand, const int* __restrict__ ws_ord,
    float* __restrict__ out_keep)
{
    __shared__ u64  cl[2][CHUNK * WSTRIDE];   // 16 KB double buffer
    __shared__ int   ord[NQ];
    __shared__ float kf[NQ];
    int b = blockIdx.x, t = threadIdx.x;
    int lane = t & 63, wv = t >> 6;
    const u64* src = cand + (size_t)b * NQ * WSTRIDE;

    for (int k = t; k < CHUNK * WSTRIDE; k += 256) cl[0][k] = src[k];
    for (int k = t; k < NQ; k += 256) ord[k] = ws_ord[b * NQ + k];
    __syncthreads();

    const int nch = (NQ + CHUNK - 1) / CHUNK;   // 15
    u64 remv = 0ull;
    for (int ch = 0; ch < nch; ++ch) {
        // waves 1..3: prefetch next chunk
        if (wv > 0 && ch + 1 < nch) {
            int gbase = (ch + 1) * CHUNK * WSTRIDE;
            int cnt = min(CHUNK, NQ - (ch + 1) * CHUNK) * WSTRIDE;
            for (int k = t - 64; k < cnt; k += 192)
                cl[(ch + 1) & 1][k] = src[gbase + k];
        }
        // wave 0: sequential greedy over this chunk
        if (wv == 0) {
            int rows = min(CHUNK, NQ - ch * CHUNK);
            const u64* C = cl[ch & 1];
            for (int r = 0; r < rows; ++r) {
                int i = ch * CHUNK + r;
                int wi = i >> 6, bi = i & 63;
                int sup = __any((int)((lane == wi) && ((remv >> bi) & 1ull)));
                u64 c = C[r * WSTRIDE + (lane & 15)];
                u64 msk = (!sup && lane < NWORD) ? ~0ull : 0ull;
                remv |= (c & msk);
                if (lane == 0) kf[i] = sup ? 0.0f : 1.0f;
            }
        }
        __syncthreads();
    }
    for (int k = t; k < NQ; k += 256) out_keep[b * NQ + ord[k]] = kf[k];
}

extern "C" void kernel_launch(void* const* d_in, const int* in_sizes, int n_in,
                              void* d_out, int out_size, void* d_ws, size_t ws_size,
                              hipStream_t stream)
{
    const float* obj_logits   = (const float*)d_in[0];
    const float* verb_logits  = (const float*)d_in[1];
    const float* sub_boxes    = (const float*)d_in[2];
    const float* obj_boxes    = (const float*)d_in[3];
    const int*   target_sizes = (const int*)d_in[4];
    const float* cmat         = (const float*)d_in[5];

    float* out      = (float*)d_out;
    float* out_hoi  = out;
    float* out_lab  = out_hoi + (size_t)NBQ * NVERB;
    float* out_sb   = out_lab + NBQ;
    float* out_ob   = out_sb + (size_t)NBQ * 4;
    float* out_keep = out_ob + (size_t)NBQ * 4;

    // workspace layout (16B-aligned first)
    char* w = (char*)d_ws;
    float4* sbox4 = (float4*)w;                       w += (size_t)NBQ * 16;
    float4* obox4 = (float4*)w;                       w += (size_t)NBQ * 16;
    u64*    cand  = (u64*)w;                          w += (size_t)NBQ * WSTRIDE * 8;
    float*  ws_max = (float*)w;                       w += (size_t)NBQ * 4;
    float*  sar   = (float*)w;                        w += (size_t)NBQ * 4;
    float*  oar   = (float*)w;                        w += (size_t)NBQ * 4;
    int*    ws_lab = (int*)w;                         w += (size_t)NBQ * 4;
    int*    slab  = (int*)w;                          w += (size_t)NBQ * 4;
    int*    ws_ord = (int*)w;                         w += (size_t)NBQ * 4;

    kA<<<NBQ / 4, 256, 0, stream>>>(obj_logits, verb_logits, sub_boxes, obj_boxes,
                                    target_sizes, cmat,
                                    out_hoi, out_lab, out_sb, out_ob, ws_max, ws_lab);
    kB<<<dim3(4, NB), 256, 0, stream>>>(ws_max, ws_lab, out_sb, out_ob, ws_ord,
                                        sbox4, obox4, sar, oar, slab);
    kC<<<dim3(15, NB), 256, 0, stream>>>(sbox4, obox4, sar, oar, slab, cand);
    kD<<<NB, 256, 0, stream>>>(cand, ws_ord, out_keep);
}

// Round 3
// 180.234 us; speedup vs baseline: 1.3290x; 1.1420x over previous
//
#include <hip/hip_runtime.h>

typedef unsigned long long u64;

#define NB 64
#define NQ 900
#define NCLS 81     // C+1
#define NVERB 117
#define NBQ (NB*NQ)
#define NWORD 15    // ceil(900/64)
#define WSTRIDE 16  // padded words per cand row

// ---------------- Kernel A: per-(b,q) scores/labels/boxes, one wave each ----
__global__ __launch_bounds__(256) void kA(
    const float* __restrict__ obj_logits, const float* __restrict__ verb_logits,
    const float* __restrict__ sub_boxes, const float* __restrict__ obj_boxes,
    const int* __restrict__ target_sizes, const float* __restrict__ cmat,
    float* __restrict__ out_hoi, float* __restrict__ out_lab,
    float* __restrict__ out_sb, float* __restrict__ out_ob,
    float* __restrict__ ws_max, int* __restrict__ ws_lab)
{
    int wid  = (blockIdx.x * blockDim.x + threadIdx.x) >> 6;
    int lane = threadIdx.x & 63;
    if (wid >= NBQ) return;
    int b = wid / NQ;

    // max + argmax over 81 logits (first-index tie-break)
    const float* ol = obj_logits + (size_t)wid * NCLS;
    float m  = ol[lane];
    int   mi = lane;
    if (lane < NCLS - 64) {
        float v1 = ol[64 + lane];
        if (v1 > m) { m = v1; mi = 64 + lane; }   // strict >: keeps smaller index
    }
    for (int off = 32; off; off >>= 1) {
        float om  = __shfl_xor(m, off);
        int   omi = __shfl_xor(mi, off);
        if (om > m || (om == m && omi < mi)) { m = om; mi = omi; }
    }
    float obj_score = 1.0f / (1.0f + expf(-m));
    if (lane == 0) { out_lab[wid] = (float)mi; ws_lab[wid] = mi; }

    // verb sigmoids * obj_score * mask; row max
    const float* vl = verb_logits + (size_t)wid * NVERB;
    float* oh = out_hoi + (size_t)wid * NVERB;
    float mx = -1.0f;                       // all hoi scores >= 0
    for (int v = lane; v < NVERB; v += 64) {
        float s = 1.0f / (1.0f + expf(-vl[v]));
        float msk = (mi < NCLS - 1) ? cmat[v * (NCLS - 1) + mi] : 1.0f;
        float h = s * obj_score * msk;
        oh[v] = h;
        mx = fmaxf(mx, h);
    }
    for (int off = 32; off; off >>= 1) mx = fmaxf(mx, __shfl_xor(mx, off));
    if (lane == 0) ws_max[wid] = mx;

    // scaled xyxy boxes (lane 0: subject, lane 1: object)
    if (lane < 2) {
        const float* bx = (lane == 0 ? sub_boxes : obj_boxes) + (size_t)wid * 4;
        float* o = (lane == 0 ? out_sb : out_ob) + (size_t)wid * 4;
        float cx = bx[0], cy = bx[1], w = bx[2], h = bx[3];
        float ih = (float)target_sizes[b * 2 + 0];
        float iw = (float)target_sizes[b * 2 + 1];
        o[0] = (cx - 0.5f * w) * iw;
        o[1] = (cy - 0.5f * h) * ih;
        o[2] = (cx + 0.5f * w) * iw;
        o[3] = (cy + 0.5f * h) * ih;
    }
}

// ------------- Kernel B: rank-by-count sort, grid=(4 q-chunks, NB) ---------
__global__ __launch_bounds__(256) void kB(
    const float* __restrict__ ws_max, const int* __restrict__ ws_lab,
    const float* __restrict__ out_sb, const float* __restrict__ out_ob,
    int* __restrict__ ws_ord,
    float4* __restrict__ sbox4, float4* __restrict__ obox4,
    float* __restrict__ sar, float* __restrict__ oar,
    int* __restrict__ slab)
{
    __shared__ float sc[NQ];
    int b = blockIdx.y, t = threadIdx.x;
    for (int i = t; i < NQ; i += 256) sc[i] = ws_max[b * NQ + i];
    __syncthreads();
    int q = blockIdx.x * 256 + t;
    if (q >= NQ) return;
    float sq = sc[q];
    int rank = 0;
    #pragma unroll 4
    for (int j = 0; j < NQ; ++j) {
        float sj = sc[j];
        rank += (sj > sq) || (sj == sq && j < q);
    }
    int src = b * NQ + q, dst = b * NQ + rank;
    ws_ord[dst] = q;
    float4 s4 = *reinterpret_cast<const float4*>(out_sb + (size_t)src * 4);
    float4 o4 = *reinterpret_cast<const float4*>(out_ob + (size_t)src * 4);
    sbox4[dst] = s4;
    obox4[dst] = o4;
    sar[dst] = (s4.z - s4.x + 1.0f) * (s4.w - s4.y + 1.0f);
    oar[dst] = (o4.z - o4.x + 1.0f) * (o4.w - o4.y + 1.0f);
    slab[dst] = ws_lab[src];
}

// ------- Kernel C: cand bitmask, LDS-staged batch, grid=(15 chunks, NB) ----
__global__ __launch_bounds__(256) void kC(
    const float4* __restrict__ sbox4, const float4* __restrict__ obox4,
    const float* __restrict__ sar, const float* __restrict__ oar,
    const int* __restrict__ slab, u64* __restrict__ cand)
{
    __shared__ float4 Lsb[NQ];
    __shared__ float4 Lob[NQ];
    __shared__ float  Lsa[NQ];
    __shared__ float  Loa[NQ];
    __shared__ int    Llab[NQ];
    int b = blockIdx.y, t = threadIdx.x;
    int base = b * NQ;
    for (int k = t; k < NQ; k += 256) {
        Lsb[k] = sbox4[base + k];
        Lob[k] = obox4[base + k];
        Lsa[k] = sar[base + k];
        Loa[k] = oar[base + k];
        Llab[k] = slab[base + k];
    }
    __syncthreads();

    int lane = t & 63, wv = t >> 6;
    for (int r = wv; r < 60; r += 4) {
        int i = blockIdx.x * 60 + r;
        float4 si = Lsb[i]; float sari = Lsa[i];
        float4 oi = Lob[i]; float oari = Loa[i];
        int li = Llab[i];
        u64* crow = cand + ((size_t)base + i) * WSTRIDE;
        int w0 = i >> 6;
        if (lane < w0) crow[lane] = 0ull;   // zero lower-triangle words
        for (int wj = w0; wj < NWORD; ++wj) {
            int j = wj * 64 + lane;
            int jc = j < NQ ? j : NQ - 1;
            bool cl = (j > i) && (j < NQ) && (Llab[jc] == li);
            u64 bal = 0ull;
            if (__any((int)cl)) {
                float4 sj = Lsb[jc];
                float4 oj = Lob[jc];
                float xx1 = fmaxf(si.x, sj.x), yy1 = fmaxf(si.y, sj.y);
                float xx2 = fminf(si.z, sj.z), yy2 = fminf(si.w, sj.w);
                float w = fmaxf(0.0f, xx2 - xx1 + 1.0f);
                float h = fmaxf(0.0f, yy2 - yy1 + 1.0f);
                float iS = w * h;
                float uS = sari + Lsa[jc] - iS;
                xx1 = fmaxf(oi.x, oj.x); yy1 = fmaxf(oi.y, oj.y);
                xx2 = fminf(oi.z, oj.z); yy2 = fminf(oi.w, oj.w);
                w = fmaxf(0.0f, xx2 - xx1 + 1.0f);
                h = fmaxf(0.0f, yy2 - yy1 + 1.0f);
                float iO = w * h;
                float uO = oari + Loa[jc] - iO;
                // iouS * sqrt(iouO) > 0.7  <=>  iS^2*iO > 0.49*uS^2*uO  (all >= 0, unions >= 1)
                bool pred = cl && (iS * iS * iO > 0.49f * uS * uS * uO);
                bal = __ballot((int)pred);
            }
            if (lane == 0) crow[wj] = bal;
        }
    }
}

// ------- Kernel D: chunked greedy, in-register 64x64 resolution ------------
#define CHUNK 64
__global__ __launch_bounds__(256) void kD(
    const u64* __restrict__ cand, const int* __restrict__ ws_ord,
    float* __restrict__ out_keep)
{
    __shared__ u64  cl[2][CHUNK * WSTRIDE];   // 16 KB double buffer
    __shared__ int  ord[NQ];
    __shared__ u64  keepw[NWORD];
    int b = blockIdx.x, t = threadIdx.x;
    int lane = t & 63, wv = t >> 6;
    const u64* src = cand + (size_t)b * NQ * WSTRIDE;

    for (int k = t; k < CHUNK * WSTRIDE; k += 256) cl[0][k] = src[k];
    for (int k = t; k < NQ; k += 256) ord[k] = ws_ord[b * NQ + k];
    __syncthreads();

    const int nch = (NQ + CHUNK - 1) / CHUNK;   // 15 (last chunk: 4 rows)
    u64 remv = 0ull;    // lane w (w<NWORD) holds suppressed-mask word w
    for (int ch = 0; ch < nch; ++ch) {
        // waves 1..3: prefetch next chunk
        if (wv > 0 && ch + 1 < nch) {
            int gbase = (ch + 1) * CHUNK * WSTRIDE;
            int cnt = min(CHUNK, NQ - (ch + 1) * CHUNK) * WSTRIDE;
            for (int k = t - 64; k < cnt; k += 192)
                cl[(ch + 1) & 1][k] = src[gbase + k];
        }
        // wave 0: resolve this chunk
        if (wv == 0) {
            const u64* C = cl[ch & 1];
            int rows = min(CHUNK, NQ - ch * CHUNK);
            u64 inc = __shfl(remv, ch);               // incoming suppressed word
            u64 introw = (lane < rows) ? C[lane * WSTRIDE + ch] : 0ull;
            // sequential 64-row resolution, ~3 VALU per row (static readlane)
            u64 supp = inc;
            #pragma unroll
            for (int r = 0; r < CHUNK; ++r) {
                u64 rowr = __shfl(introw, r);
                if (!((supp >> r) & 1ull)) supp |= rowr;
            }
            u64 keep = ~supp;
            // apply kept rows' suppression to future words (parallel)
            int w = lane & 15, g = lane >> 4;
            u64 acc = 0ull;
            #pragma unroll
            for (int k = 0; k < 16; ++k) {
                int r = g * 16 + k;
                u64 c = C[r * WSTRIDE + w];
                if (((keep >> r) & 1ull) && r < rows) acc |= c;
            }
            acc |= __shfl_xor(acc, 16);
            acc |= __shfl_xor(acc, 32);
            remv |= acc;                              // lane w<15: word w
            if (lane == 0) keepw[ch] = keep;
        }
        __syncthreads();
    }
    for (int k = t; k < NQ; k += 256)
        out_keep[b * NQ + ord[k]] = ((keepw[k >> 6] >> (k & 63)) & 1ull) ? 1.0f : 0.0f;
}

extern "C" void kernel_launch(void* const* d_in, const int* in_sizes, int n_in,
                              void* d_out, int out_size, void* d_ws, size_t ws_size,
                              hipStream_t stream)
{
    const float* obj_logits   = (const float*)d_in[0];
    const float* verb_logits  = (const float*)d_in[1];
    const float* sub_boxes    = (const float*)d_in[2];
    const float* obj_boxes    = (const float*)d_in[3];
    const int*   target_sizes = (const int*)d_in[4];
    const float* cmat         = (const float*)d_in[5];

    float* out      = (float*)d_out;
    float* out_hoi  = out;
    float* out_lab  = out_hoi + (size_t)NBQ * NVERB;
    float* out_sb   = out_lab + NBQ;
    float* out_ob   = out_sb + (size_t)NBQ * 4;
    float* out_keep = out_ob + (size_t)NBQ * 4;

    // workspace layout (16B-aligned first)
    char* w = (char*)d_ws;
    float4* sbox4 = (float4*)w;                       w += (size_t)NBQ * 16;
    float4* obox4 = (float4*)w;                       w += (size_t)NBQ * 16;
    u64*    cand  = (u64*)w;                          w += (size_t)NBQ * WSTRIDE * 8;
    float*  ws_max = (float*)w;                       w += (size_t)NBQ * 4;
    float*  sar   = (float*)w;                        w += (size_t)NBQ * 4;
    float*  oar   = (float*)w;                        w += (size_t)NBQ * 4;
    int*    ws_lab = (int*)w;                         w += (size_t)NBQ * 4;
    int*    slab  = (int*)w;                          w += (size_t)NBQ * 4;
    int*    ws_ord = (int*)w;                         w += (size_t)NBQ * 4;

    kA<<<NBQ / 4, 256, 0, stream>>>(obj_logits, verb_logits, sub_boxes, obj_boxes,
                                    target_sizes, cmat,
                                    out_hoi, out_lab, out_sb, out_ob, ws_max, ws_lab);
    kB<<<dim3(4, NB), 256, 0, stream>>>(ws_max, ws_lab, out_sb, out_ob, ws_ord,
                                        sbox4, obox4, sar, oar, slab);
    kC<<<dim3(15, NB), 256, 0, stream>>>(sbox4, obox4, sar, oar, slab, cand);
    kD<<<NB, 256, 0, stream>>>(cand, ws_ord, out_keep);
}

// Round 4
// 165.763 us; speedup vs baseline: 1.4450x; 1.0873x over previous
//
#include <hip/hip_runtime.h>

typedef unsigned long long u64;

#define NB 64
#define NQ 900
#define NCLS 81     // C+1
#define NVERB 117
#define NBQ (NB*NQ)
#define NWORD 15    // ceil(900/64)
#define WSTRIDE 16  // padded words per cand row

// ---------------- Kernel A: per-(b,q) scores/labels/boxes, one wave each ----
__global__ __launch_bounds__(256) void kA(
    const float* __restrict__ obj_logits, const float* __restrict__ verb_logits,
    const float* __restrict__ sub_boxes, const float* __restrict__ obj_boxes,
    const int* __restrict__ target_sizes, const float* __restrict__ cmat,
    float* __restrict__ out_hoi, float* __restrict__ out_lab,
    float* __restrict__ out_sb, float* __restrict__ out_ob,
    float* __restrict__ ws_max, int* __restrict__ ws_lab)
{
    int wid  = (blockIdx.x * blockDim.x + threadIdx.x) >> 6;
    int lane = threadIdx.x & 63;
    if (wid >= NBQ) return;
    int b = wid / NQ;

    // max + argmax over 81 logits (first-index tie-break)
    const float* ol = obj_logits + (size_t)wid * NCLS;
    float m  = ol[lane];
    int   mi = lane;
    if (lane < NCLS - 64) {
        float v1 = ol[64 + lane];
        if (v1 > m) { m = v1; mi = 64 + lane; }   // strict >: keeps smaller index
    }
    for (int off = 32; off; off >>= 1) {
        float om  = __shfl_xor(m, off);
        int   omi = __shfl_xor(mi, off);
        if (om > m || (om == m && omi < mi)) { m = om; mi = omi; }
    }
    float obj_score = 1.0f / (1.0f + expf(-m));
    if (lane == 0) { out_lab[wid] = (float)mi; ws_lab[wid] = mi; }

    // verb sigmoids * obj_score * mask; row max
    const float* vl = verb_logits + (size_t)wid * NVERB;
    float* oh = out_hoi + (size_t)wid * NVERB;
    float mx = -1.0f;                       // all hoi scores >= 0
    for (int v = lane; v < NVERB; v += 64) {
        float s = 1.0f / (1.0f + expf(-vl[v]));
        float msk = (mi < NCLS - 1) ? cmat[v * (NCLS - 1) + mi] : 1.0f;
        float h = s * obj_score * msk;
        oh[v] = h;
        mx = fmaxf(mx, h);
    }
    for (int off = 32; off; off >>= 1) mx = fmaxf(mx, __shfl_xor(mx, off));
    if (lane == 0) ws_max[wid] = mx;

    // scaled xyxy boxes (lane 0: subject, lane 1: object)
    if (lane < 2) {
        const float* bx = (lane == 0 ? sub_boxes : obj_boxes) + (size_t)wid * 4;
        float* o = (lane == 0 ? out_sb : out_ob) + (size_t)wid * 4;
        float cx = bx[0], cy = bx[1], w = bx[2], h = bx[3];
        float ih = (float)target_sizes[b * 2 + 0];
        float iw = (float)target_sizes[b * 2 + 1];
        o[0] = (cx - 0.5f * w) * iw;
        o[1] = (cy - 0.5f * h) * ih;
        o[2] = (cx + 0.5f * w) * iw;
        o[3] = (cy + 0.5f * h) * ih;
    }
}

// ------------- Kernel B: rank-by-count sort, grid=(4 q-chunks, NB) ---------
__global__ __launch_bounds__(256) void kB(
    const float* __restrict__ ws_max, const int* __restrict__ ws_lab,
    const float* __restrict__ out_sb, const float* __restrict__ out_ob,
    int* __restrict__ ws_ord,
    float4* __restrict__ sbox4, float4* __restrict__ obox4,
    float* __restrict__ sar, float* __restrict__ oar,
    int* __restrict__ slab)
{
    __shared__ float sc[NQ];
    int b = blockIdx.y, t = threadIdx.x;
    for (int i = t; i < NQ; i += 256) sc[i] = ws_max[b * NQ + i];
    __syncthreads();
    int q = blockIdx.x * 256 + t;
    if (q >= NQ) return;
    float sq = sc[q];
    int rank = 0;
    #pragma unroll 4
    for (int j = 0; j < NQ; ++j) {
        float sj = sc[j];
        rank += (sj > sq) || (sj == sq && j < q);
    }
    int src = b * NQ + q, dst = b * NQ + rank;
    ws_ord[dst] = q;
    float4 s4 = *reinterpret_cast<const float4*>(out_sb + (size_t)src * 4);
    float4 o4 = *reinterpret_cast<const float4*>(out_ob + (size_t)src * 4);
    sbox4[dst] = s4;
    obox4[dst] = o4;
    sar[dst] = (s4.z - s4.x + 1.0f) * (s4.w - s4.y + 1.0f);
    oar[dst] = (o4.z - o4.x + 1.0f) * (o4.w - o4.y + 1.0f);
    slab[dst] = ws_lab[src];
}

// ------- Kernel C: register-tiled 64x64 cand bitmask, one wave per tile ----
// Writes ONLY upper-triangle words (tj >= ti); kD never reads the rest.
__global__ __launch_bounds__(256) void kC(
    const float4* __restrict__ sbox4, const float4* __restrict__ obox4,
    const float* __restrict__ sar, const float* __restrict__ oar,
    const int* __restrict__ slab, u64* __restrict__ cand)
{
    int b = blockIdx.y;
    int base = b * NQ;
    int lane = threadIdx.x & 63, wv = threadIdx.x >> 6;
    int tl = blockIdx.x * 4 + wv;          // 0..119 upper-triangle tile id
    int ti = 0;
    while (tl >= NWORD - ti) { tl -= NWORD - ti; ++ti; }
    int tj = ti + tl;

    // lane j data (columns of the tile), registers only
    int j = tj * 64 + lane;
    int jc = min(j, NQ - 1);
    float4 sj = sbox4[base + jc];
    float4 oj = obox4[base + jc];
    float  saj = sar[base + jc];
    float  oaj = oar[base + jc];
    int    lj  = (j < NQ) ? slab[base + jc] : -1;

    // lane i data (rows of the tile), broadcast via readlane in the loop
    int il = ti * 64 + lane;
    int ic = min(il, NQ - 1);
    float4 siL = sbox4[base + ic];
    float4 oiL = obox4[base + ic];
    float  saiL = sar[base + ic];
    float  oaiL = oar[base + ic];
    int    liL  = slab[base + ic];

    u64 myword = 0ull;
    #pragma unroll
    for (int r = 0; r < 64; ++r) {
        int i = ti * 64 + r;
        if (i < NQ) {                      // wave-uniform guard (partial tile 14)
            int li = __shfl(liL, r);
            bool cl = (j > i) && (lj == li);   // invalid j has lj==-1 -> false
            u64 bal = 0ull;
            if (__any((int)cl)) {
                float six = __shfl(siL.x, r), siy = __shfl(siL.y, r);
                float siz = __shfl(siL.z, r), siw = __shfl(siL.w, r);
                float oix = __shfl(oiL.x, r), oiy = __shfl(oiL.y, r);
                float oiz = __shfl(oiL.z, r), oiw = __shfl(oiL.w, r);
                float sai = __shfl(saiL, r),  oai = __shfl(oaiL, r);
                float xx1 = fmaxf(six, sj.x), yy1 = fmaxf(siy, sj.y);
                float xx2 = fminf(siz, sj.z), yy2 = fminf(siw, sj.w);
                float w = fmaxf(0.0f, xx2 - xx1 + 1.0f);
                float h = fmaxf(0.0f, yy2 - yy1 + 1.0f);
                float iS = w * h;
                float uS = sai + saj - iS;
                xx1 = fmaxf(oix, oj.x); yy1 = fmaxf(oiy, oj.y);
                xx2 = fminf(oiz, oj.z); yy2 = fminf(oiw, oj.w);
                w = fmaxf(0.0f, xx2 - xx1 + 1.0f);
                h = fmaxf(0.0f, yy2 - yy1 + 1.0f);
                float iO = w * h;
                float uO = oai + oaj - iO;
                // iouS * sqrt(iouO) > 0.7  <=>  iS^2*iO > 0.49*uS^2*uO
                bool pred = cl && (iS * iS * iO > 0.49f * uS * uS * uO);
                bal = __ballot((int)pred);
            }
            if (lane == r) myword = bal;   // lane r keeps row i's word
        }
    }
    if (il < NQ) cand[(size_t)(base + il) * WSTRIDE + tj] = myword;
}

// ------- Kernel D: chunked greedy, in-register 64x64 resolution ------------
#define CHUNK 64
__global__ __launch_bounds__(256) void kD(
    const u64* __restrict__ cand, const int* __restrict__ ws_ord,
    float* __restrict__ out_keep)
{
    __shared__ u64  cl[2][CHUNK * WSTRIDE];   // 16 KB double buffer
    __shared__ int  ord[NQ];
    __shared__ u64  keepw[NWORD];
    int b = blockIdx.x, t = threadIdx.x;
    int lane = t & 63, wv = t >> 6;
    const u64* src = cand + (size_t)b * NQ * WSTRIDE;

    for (int k = t; k < CHUNK * WSTRIDE; k += 256) cl[0][k] = src[k];
    for (int k = t; k < NQ; k += 256) ord[k] = ws_ord[b * NQ + k];
    __syncthreads();

    const int nch = (NQ + CHUNK - 1) / CHUNK;   // 15 (last chunk: 4 rows)
    u64 remv = 0ull;    // lane l holds suppressed-mask word (l & 15)
    for (int ch = 0; ch < nch; ++ch) {
        // waves 1..3: prefetch next chunk
        if (wv > 0 && ch + 1 < nch) {
            int gbase = (ch + 1) * CHUNK * WSTRIDE;
            int cnt = min(CHUNK, NQ - (ch + 1) * CHUNK) * WSTRIDE;
            for (int k = t - 64; k < cnt; k += 192)
                cl[(ch + 1) & 1][k] = src[gbase + k];
        }
        // wave 0: resolve this chunk
        if (wv == 0) {
            const u64* C = cl[ch & 1];
            int rows = min(CHUNK, NQ - ch * CHUNK);
            u64 inc = __shfl(remv, ch);               // incoming suppressed word
            u64 introw = (lane < rows) ? C[lane * WSTRIDE + ch] : 0ull;
            // sequential 64-row resolution (static readlane chain)
            u64 supp = inc;
            #pragma unroll
            for (int r = 0; r < CHUNK; ++r) {
                u64 rowr = __shfl(introw, r);
                if (!((supp >> r) & 1ull)) supp |= rowr;
            }
            u64 keep = ~supp;
            // apply kept rows' suppression to FUTURE words only (w > ch)
            int w = lane & 15, g = lane >> 4;
            bool wok = (w > ch) && (w < NWORD);
            u64 acc = 0ull;
            #pragma unroll
            for (int k = 0; k < 16; ++k) {
                int r = g * 16 + k;
                if (wok && r < rows && ((keep >> r) & 1ull))
                    acc |= C[r * WSTRIDE + w];
            }
            acc |= __shfl_xor(acc, 16);
            acc |= __shfl_xor(acc, 32);
            remv |= acc;
            if (lane == 0) keepw[ch] = keep;
        }
        __syncthreads();
    }
    for (int k = t; k < NQ; k += 256)
        out_keep[b * NQ + ord[k]] = ((keepw[k >> 6] >> (k & 63)) & 1ull) ? 1.0f : 0.0f;
}

extern "C" void kernel_launch(void* const* d_in, const int* in_sizes, int n_in,
                              void* d_out, int out_size, void* d_ws, size_t ws_size,
                              hipStream_t stream)
{
    const float* obj_logits   = (const float*)d_in[0];
    const float* verb_logits  = (const float*)d_in[1];
    const float* sub_boxes    = (const float*)d_in[2];
    const float* obj_boxes    = (const float*)d_in[3];
    const int*   target_sizes = (const int*)d_in[4];
    const float* cmat         = (const float*)d_in[5];

    float* out      = (float*)d_out;
    float* out_hoi  = out;
    float* out_lab  = out_hoi + (size_t)NBQ * NVERB;
    float* out_sb   = out_lab + NBQ;
    float* out_ob   = out_sb + (size_t)NBQ * 4;
    float* out_keep = out_ob + (size_t)NBQ * 4;

    // workspace layout (16B-aligned first)
    char* w = (char*)d_ws;
    float4* sbox4 = (float4*)w;                       w += (size_t)NBQ * 16;
    float4* obox4 = (float4*)w;                       w += (size_t)NBQ * 16;
    u64*    cand  = (u64*)w;                          w += (size_t)NBQ * WSTRIDE * 8;
    float*  ws_max = (float*)w;                       w += (size_t)NBQ * 4;
    float*  sar   = (float*)w;                        w += (size_t)NBQ * 4;
    float*  oar   = (float*)w;                        w += (size_t)NBQ * 4;
    int*    ws_lab = (int*)w;                         w += (size_t)NBQ * 4;
    int*    slab  = (int*)w;                          w += (size_t)NBQ * 4;
    int*    ws_ord = (int*)w;                         w += (size_t)NBQ * 4;

    kA<<<NBQ / 4, 256, 0, stream>>>(obj_logits, verb_logits, sub_boxes, obj_boxes,
                                    target_sizes, cmat,
                                    out_hoi, out_lab, out_sb, out_ob, ws_max, ws_lab);
    kB<<<dim3(4, NB), 256, 0, stream>>>(ws_max, ws_lab, out_sb, out_ob, ws_ord,
                                        sbox4, obox4, sar, oar, slab);
    kC<<<dim3(30, NB), 256, 0, stream>>>(sbox4, obox4, sar, oar, slab, cand);
    kD<<<NB, 256, 0, stream>>>(cand, ws_ord, out_keep);
}

// Round 5
// 146.195 us; speedup vs baseline: 1.6384x; 1.1339x over previous
//
#include <hip/hip_runtime.h>

typedef unsigned long long u64;

#define NB 64
#define NQ 900
#define NCLS 81     // C+1
#define NVERB 117
#define NBQ (NB*NQ)
#define NWORD 15    // ceil(900/64)
#define WSTRIDE 16  // padded words per cand row (global)
#define LSTRIDE 17  // padded words per cand row (kD LDS, odd-dword phase)

// -------- Kernel A: 2 rows per wave for ILP; scores/labels/boxes ----------
__global__ __launch_bounds__(256) void kA(
    const float* __restrict__ obj_logits, const float* __restrict__ verb_logits,
    const float* __restrict__ sub_boxes, const float* __restrict__ obj_boxes,
    const int* __restrict__ target_sizes, const float* __restrict__ cmat,
    float* __restrict__ out_hoi, float* __restrict__ out_lab,
    float* __restrict__ out_sb, float* __restrict__ out_ob,
    float* __restrict__ ws_max, int* __restrict__ ws_lab)
{
    int wp   = (blockIdx.x * blockDim.x + threadIdx.x) >> 6;
    int lane = threadIdx.x & 63;
    int w0 = wp * 2;                     // rows w0, w0+1 (never cross batch: NQ even)
    if (w0 >= NBQ) return;
    int b = w0 / NQ;

    // ---- argmax over 81 logits, both rows interleaved ----
    const float* ol0 = obj_logits + (size_t)w0 * NCLS;
    const float* ol1 = ol0 + NCLS;
    float m0 = ol0[lane], m1 = ol1[lane];
    int  mi0 = lane,     mi1 = lane;
    if (lane < NCLS - 64) {
        float v0 = ol0[64 + lane]; if (v0 > m0) { m0 = v0; mi0 = 64 + lane; }
        float v1 = ol1[64 + lane]; if (v1 > m1) { m1 = v1; mi1 = 64 + lane; }
    }
    for (int off = 32; off; off >>= 1) {
        float a0 = __shfl_xor(m0, off); int c0 = __shfl_xor(mi0, off);
        float a1 = __shfl_xor(m1, off); int c1 = __shfl_xor(mi1, off);
        if (a0 > m0 || (a0 == m0 && c0 < mi0)) { m0 = a0; mi0 = c0; }
        if (a1 > m1 || (a1 == m1 && c1 < mi1)) { m1 = a1; mi1 = c1; }
    }
    float os0 = 1.0f / (1.0f + expf(-m0));
    float os1 = 1.0f / (1.0f + expf(-m1));
    if (lane == 0) {
        out_lab[w0]     = (float)mi0; ws_lab[w0]     = mi0;
        out_lab[w0 + 1] = (float)mi1; ws_lab[w0 + 1] = mi1;
    }

    // ---- verbs: sigmoid * obj_score * mask, row max, both rows ----
    const float* vl0 = verb_logits + (size_t)w0 * NVERB;
    const float* vl1 = vl0 + NVERB;
    float* oh0 = out_hoi + (size_t)w0 * NVERB;
    float* oh1 = oh0 + NVERB;
    float mx0 = -1.0f, mx1 = -1.0f;
    for (int v = lane; v < NVERB; v += 64) {
        float s0 = 1.0f / (1.0f + expf(-vl0[v]));
        float s1 = 1.0f / (1.0f + expf(-vl1[v]));
        float k0 = (mi0 < NCLS - 1) ? cmat[v * (NCLS - 1) + mi0] : 1.0f;
        float k1 = (mi1 < NCLS - 1) ? cmat[v * (NCLS - 1) + mi1] : 1.0f;
        float h0 = s0 * os0 * k0;
        float h1 = s1 * os1 * k1;
        oh0[v] = h0; oh1[v] = h1;
        mx0 = fmaxf(mx0, h0); mx1 = fmaxf(mx1, h1);
    }
    for (int off = 32; off; off >>= 1) {
        mx0 = fmaxf(mx0, __shfl_xor(mx0, off));
        mx1 = fmaxf(mx1, __shfl_xor(mx1, off));
    }
    if (lane == 0) { ws_max[w0] = mx0; ws_max[w0 + 1] = mx1; }

    // ---- scaled xyxy boxes: lanes 0-3 handle {row0,row1}x{sub,obj} ----
    if (lane < 4) {
        int row = w0 + (lane >> 1);
        const float* bx = ((lane & 1) == 0 ? sub_boxes : obj_boxes) + (size_t)row * 4;
        float* o = ((lane & 1) == 0 ? out_sb : out_ob) + (size_t)row * 4;
        float cx = bx[0], cy = bx[1], w = bx[2], h = bx[3];
        float ih = (float)target_sizes[b * 2 + 0];
        float iw = (float)target_sizes[b * 2 + 1];
        o[0] = (cx - 0.5f * w) * iw;
        o[1] = (cy - 0.5f * h) * ih;
        o[2] = (cx + 0.5f * w) * iw;
        o[3] = (cy + 0.5f * h) * ih;
    }
}

// ------------- Kernel B: rank-by-count sort, grid=(4 q-chunks, NB) ---------
__global__ __launch_bounds__(256) void kB(
    const float* __restrict__ ws_max, const int* __restrict__ ws_lab,
    const float* __restrict__ out_sb, const float* __restrict__ out_ob,
    int* __restrict__ ws_ord,
    float4* __restrict__ sbox4, float4* __restrict__ obox4,
    float* __restrict__ sar, float* __restrict__ oar,
    int* __restrict__ slab)
{
    __shared__ float sc[NQ];
    int b = blockIdx.y, t = threadIdx.x;
    for (int i = t; i < NQ; i += 256) sc[i] = ws_max[b * NQ + i];
    __syncthreads();
    int q = blockIdx.x * 256 + t;
    if (q >= NQ) return;
    float sq = sc[q];
    int rank = 0;
    #pragma unroll 4
    for (int j = 0; j < NQ; ++j) {
        float sj = sc[j];
        rank += (sj > sq) || (sj == sq && j < q);
    }
    int src = b * NQ + q, dst = b * NQ + rank;
    ws_ord[dst] = q;
    float4 s4 = *reinterpret_cast<const float4*>(out_sb + (size_t)src * 4);
    float4 o4 = *reinterpret_cast<const float4*>(out_ob + (size_t)src * 4);
    sbox4[dst] = s4;
    obox4[dst] = o4;
    sar[dst] = (s4.z - s4.x + 1.0f) * (s4.w - s4.y + 1.0f);
    oar[dst] = (o4.z - o4.x + 1.0f) * (o4.w - o4.y + 1.0f);
    slab[dst] = ws_lab[src];
}

// ------- Kernel C: register-tiled 64x64 cand bitmask, one wave per tile ----
// Writes ONLY upper-triangle words (tj >= ti); kD never reads the rest.
__global__ __launch_bounds__(256) void kC(
    const float4* __restrict__ sbox4, const float4* __restrict__ obox4,
    const float* __restrict__ sar, const float* __restrict__ oar,
    const int* __restrict__ slab, u64* __restrict__ cand)
{
    int b = blockIdx.y;
    int base = b * NQ;
    int lane = threadIdx.x & 63, wv = threadIdx.x >> 6;
    int tl = blockIdx.x * 4 + wv;          // 0..119 upper-triangle tile id
    int ti = 0;
    while (tl >= NWORD - ti) { tl -= NWORD - ti; ++ti; }
    int tj = ti + tl;

    // lane j data (columns of the tile), registers only
    int j = tj * 64 + lane;
    int jc = min(j, NQ - 1);
    float4 sj = sbox4[base + jc];
    float4 oj = obox4[base + jc];
    float  saj = sar[base + jc];
    float  oaj = oar[base + jc];
    int    lj  = (j < NQ) ? slab[base + jc] : -1;

    // lane i data (rows of the tile), broadcast via readlane in the loop
    int il = ti * 64 + lane;
    int ic = min(il, NQ - 1);
    float4 siL = sbox4[base + ic];
    float4 oiL = obox4[base + ic];
    float  saiL = sar[base + ic];
    float  oaiL = oar[base + ic];
    int    liL  = slab[base + ic];

    u64 myword = 0ull;
    #pragma unroll
    for (int r = 0; r < 64; ++r) {
        int i = ti * 64 + r;
        if (i < NQ) {                      // wave-uniform guard (partial tile 14)
            int li = __shfl(liL, r);
            bool cl = (j > i) && (lj == li);   // invalid j has lj==-1 -> false
            u64 bal = 0ull;
            if (__any((int)cl)) {
                float six = __shfl(siL.x, r), siy = __shfl(siL.y, r);
                float siz = __shfl(siL.z, r), siw = __shfl(siL.w, r);
                float oix = __shfl(oiL.x, r), oiy = __shfl(oiL.y, r);
                float oiz = __shfl(oiL.z, r), oiw = __shfl(oiL.w, r);
                float sai = __shfl(saiL, r),  oai = __shfl(oaiL, r);
                float xx1 = fmaxf(six, sj.x), yy1 = fmaxf(siy, sj.y);
                float xx2 = fminf(siz, sj.z), yy2 = fminf(siw, sj.w);
                float w = fmaxf(0.0f, xx2 - xx1 + 1.0f);
                float h = fmaxf(0.0f, yy2 - yy1 + 1.0f);
                float iS = w * h;
                float uS = sai + saj - iS;
                xx1 = fmaxf(oix, oj.x); yy1 = fmaxf(oiy, oj.y);
                xx2 = fminf(oiz, oj.z); yy2 = fminf(oiw, oj.w);
                w = fmaxf(0.0f, xx2 - xx1 + 1.0f);
                h = fmaxf(0.0f, yy2 - yy1 + 1.0f);
                float iO = w * h;
                float uO = oai + oaj - iO;
                // iouS * sqrt(iouO) > 0.7  <=>  iS^2*iO > 0.49*uS^2*uO
                bool pred = cl && (iS * iS * iO > 0.49f * uS * uS * uO);
                bal = __ballot((int)pred);
            }
            if (lane == r) myword = bal;   // lane r keeps row i's word
        }
    }
    if (il < NQ) cand[(size_t)(base + il) * WSTRIDE + tj] = myword;
}

// ------- Kernel D: chunked greedy, SALU-scalar 64x64 resolution ------------
#define CHUNK 64
__global__ __launch_bounds__(256) void kD(
    const u64* __restrict__ cand, const int* __restrict__ ws_ord,
    float* __restrict__ out_keep)
{
    __shared__ u64  cl[2][CHUNK * LSTRIDE];   // padded rows: stride-17 u64
    __shared__ int  ord[NQ];
    __shared__ u64  keepw[NWORD];
    int b = blockIdx.x, t = threadIdx.x;
    int lane = t & 63, wv = t >> 6;
    const u64* src = cand + (size_t)b * NQ * WSTRIDE;

    for (int k = t; k < CHUNK * WSTRIDE; k += 256)
        cl[0][(k >> 4) * LSTRIDE + (k & 15)] = src[k];
    for (int k = t; k < NQ; k += 256) ord[k] = ws_ord[b * NQ + k];
    __syncthreads();

    const int nch = (NQ + CHUNK - 1) / CHUNK;   // 15 (last chunk: 4 rows)
    u64 remv = 0ull;    // lane l holds suppressed-mask word (l & 15)
    for (int ch = 0; ch < nch; ++ch) {
        // waves 1..3: prefetch next chunk
        if (wv > 0 && ch + 1 < nch) {
            int gbase = (ch + 1) * CHUNK * WSTRIDE;
            int cnt = min(CHUNK, NQ - (ch + 1) * CHUNK) * WSTRIDE;
            for (int k = t - 64; k < cnt; k += 192)
                cl[(ch + 1) & 1][(k >> 4) * LSTRIDE + (k & 15)] = src[gbase + k];
        }
        // wave 0: resolve this chunk
        if (wv == 0) {
            const u64* C = cl[ch & 1];
            int rows = min(CHUNK, NQ - ch * CHUNK);
            // incoming suppressed word -> SGPR via readlane (remv word ch is in lane ch)
            unsigned inc_lo = __builtin_amdgcn_readlane((unsigned)remv, ch);
            unsigned inc_hi = __builtin_amdgcn_readlane((unsigned)(remv >> 32), ch);
            u64 introw = (lane < rows) ? C[lane * LSTRIDE + ch] : 0ull;
            unsigned ilo = (unsigned)introw, ihi = (unsigned)(introw >> 32);
            // sequential 64-row resolution, all wave-uniform -> SALU chain
            u64 supp = ((u64)inc_hi << 32) | inc_lo;
            #pragma unroll
            for (int r = 0; r < CHUNK; ++r) {
                u64 rowr = ((u64)__builtin_amdgcn_readlane(ihi, r) << 32)
                         |  (u64)__builtin_amdgcn_readlane(ilo, r);
                supp |= ((supp >> r) & 1ull) ? 0ull : rowr;
            }
            u64 keep = ~supp;
            // apply kept rows' suppression to FUTURE words only (w > ch)
            int w = lane & 15, g = lane >> 4;
            bool wok = (w > ch) && (w < NWORD);
            u64 acc = 0ull;
            #pragma unroll
            for (int k = 0; k < 16; ++k) {
                int r = g * 16 + k;
                u64 c = C[r * LSTRIDE + w];     // unconditional, pipelined
                if (wok && r < rows && ((keep >> r) & 1ull)) acc |= c;
            }
            acc |= __shfl_xor(acc, 16);
            acc |= __shfl_xor(acc, 32);
            remv |= acc;
            if (lane == 0) keepw[ch] = keep;
        }
        __syncthreads();
    }
    for (int k = t; k < NQ; k += 256)
        out_keep[b * NQ + ord[k]] = ((keepw[k >> 6] >> (k & 63)) & 1ull) ? 1.0f : 0.0f;
}

extern "C" void kernel_launch(void* const* d_in, const int* in_sizes, int n_in,
                              void* d_out, int out_size, void* d_ws, size_t ws_size,
                              hipStream_t stream)
{
    const float* obj_logits   = (const float*)d_in[0];
    const float* verb_logits  = (const float*)d_in[1];
    const float* sub_boxes    = (const float*)d_in[2];
    const float* obj_boxes    = (const float*)d_in[3];
    const int*   target_sizes = (const int*)d_in[4];
    const float* cmat         = (const float*)d_in[5];

    float* out      = (float*)d_out;
    float* out_hoi  = out;
    float* out_lab  = out_hoi + (size_t)NBQ * NVERB;
    float* out_sb   = out_lab + NBQ;
    float* out_ob   = out_sb + (size_t)NBQ * 4;
    float* out_keep = out_ob + (size_t)NBQ * 4;

    // workspace layout (16B-aligned first)
    char* w = (char*)d_ws;
    float4* sbox4 = (float4*)w;                       w += (size_t)NBQ * 16;
    float4* obox4 = (float4*)w;                       w += (size_t)NBQ * 16;
    u64*    cand  = (u64*)w;                          w += (size_t)NBQ * WSTRIDE * 8;
    float*  ws_max = (float*)w;                       w += (size_t)NBQ * 4;
    float*  sar   = (float*)w;                        w += (size_t)NBQ * 4;
    float*  oar   = (float*)w;                        w += (size_t)NBQ * 4;
    int*    ws_lab = (int*)w;                         w += (size_t)NBQ * 4;
    int*    slab  = (int*)w;                          w += (size_t)NBQ * 4;
    int*    ws_ord = (int*)w;                         w += (size_t)NBQ * 4;

    kA<<<NBQ / 8, 256, 0, stream>>>(obj_logits, verb_logits, sub_boxes, obj_boxes,
                                    target_sizes, cmat,
                                    out_hoi, out_lab, out_sb, out_ob, ws_max, ws_lab);
    kB<<<dim3(4, NB), 256, 0, stream>>>(ws_max, ws_lab, out_sb, out_ob, ws_ord,
                                        sbox4, obox4, sar, oar, slab);
    kC<<<dim3(30, NB), 256, 0, stream>>>(sbox4, obox4, sar, oar, slab, cand);
    kD<<<NB, 256, 0, stream>>>(cand, ws_ord, out_keep);
}

// Round 6
// 137.169 us; speedup vs baseline: 1.7462x; 1.0658x over previous
//
#include <hip/hip_runtime.h>

typedef unsigned long long u64;

#define NB 64
#define NQ 900
#define NCLS 81     // C+1
#define NVERB 117
#define NBQ (NB*NQ)
#define NWORD 15    // ceil(900/64)
#define WSTRIDE 16  // padded words per cand row (global)
#define LSTRIDE 17  // padded words per cand row (kD LDS, odd-dword phase)

// -------- Kernel 0: transpose correct_mat -> cmatT[81][117], row 80 = 1 ----
__global__ __launch_bounds__(256) void k0(
    const float* __restrict__ cmat, float* __restrict__ cmatT)
{
    int idx = blockIdx.x * 256 + threadIdx.x;
    if (idx >= NCLS * NVERB) return;
    int c = idx / NVERB, v = idx - c * NVERB;
    cmatT[idx] = (c < NCLS - 1) ? cmat[v * (NCLS - 1) + c] : 1.0f;
}

// -------- Kernel A: 4 rows/wave, ballot-argmax, coalesced mask loads -------
__global__ __launch_bounds__(256) void kA(
    const float* __restrict__ obj_logits, const float* __restrict__ verb_logits,
    const float* __restrict__ sub_boxes, const float* __restrict__ obj_boxes,
    const int* __restrict__ target_sizes, const float* __restrict__ cmatT,
    float* __restrict__ out_hoi, float* __restrict__ out_lab,
    float* __restrict__ out_sb, float* __restrict__ out_ob,
    float* __restrict__ ws_max, int* __restrict__ ws_lab)
{
    int wp   = (blockIdx.x * blockDim.x + threadIdx.x) >> 6;
    int lane = threadIdx.x & 63;
    int w0 = wp * 4;                 // 4 rows; 900 % 4 == 0 -> never cross batch
    int b = w0 / NQ;

    // ---- argmax over 81 logits: max-butterfly + ballot index recovery ----
    float OS[4]; int MI[4];
    #pragma unroll
    for (int r = 0; r < 4; ++r) {
        const float* ol = obj_logits + (size_t)(w0 + r) * NCLS;
        float A  = ol[lane];
        float Bv = (lane < NCLS - 64) ? ol[64 + lane] : -3.4e38f;
        float m = fmaxf(A, Bv);
        #pragma unroll
        for (int off = 32; off; off >>= 1) m = fmaxf(m, __shfl_xor(m, off));
        u64 balA = __ballot((int)(A == m));
        u64 balB = __ballot((int)(lane < NCLS - 64 && Bv == m));
        MI[r] = balA ? (__ffsll(balA) - 1) : (63 + __ffsll(balB));
        OS[r] = 1.0f / (1.0f + __expf(-m));
    }

    // ---- verbs: sigmoid * obj_score * maskT (coalesced), row max ----
    float MX[4];
    #pragma unroll
    for (int r = 0; r < 4; ++r) {
        const float* vl  = verb_logits + (size_t)(w0 + r) * NVERB;
        float*       oh  = out_hoi     + (size_t)(w0 + r) * NVERB;
        const float* cmr = cmatT + MI[r] * NVERB;
        float sa = vl[lane];
        float ka = cmr[lane];
        float ha = OS[r] * ka / (1.0f + __expf(-sa));
        float hb = -1.0f;
        if (lane < NVERB - 64) {
            float sb = vl[64 + lane];
            float kb = cmr[64 + lane];
            hb = OS[r] * kb / (1.0f + __expf(-sb));
            oh[64 + lane] = hb;
        }
        oh[lane] = ha;
        float mx = fmaxf(ha, hb);
        #pragma unroll
        for (int off = 32; off; off >>= 1) mx = fmaxf(mx, __shfl_xor(mx, off));
        MX[r] = mx;
    }

    // ---- scalar per-row outputs (values are wave-uniform) ----
    if (lane < 4) {
        int   mi = (lane == 0) ? MI[0] : (lane == 1) ? MI[1] : (lane == 2) ? MI[2] : MI[3];
        float mx = (lane == 0) ? MX[0] : (lane == 1) ? MX[1] : (lane == 2) ? MX[2] : MX[3];
        out_lab[w0 + lane] = (float)mi;
        ws_lab[w0 + lane]  = mi;
        ws_max[w0 + lane]  = mx;
    }

    // ---- scaled xyxy boxes: lanes 0-7 = {4 rows} x {sub,obj} ----
    if (lane < 8) {
        int row = w0 + (lane >> 1);
        const float* bx = ((lane & 1) == 0 ? sub_boxes : obj_boxes) + (size_t)row * 4;
        float* o = ((lane & 1) == 0 ? out_sb : out_ob) + (size_t)row * 4;
        float cx = bx[0], cy = bx[1], w = bx[2], h = bx[3];
        float ih = (float)target_sizes[b * 2 + 0];
        float iw = (float)target_sizes[b * 2 + 1];
        o[0] = (cx - 0.5f * w) * iw;
        o[1] = (cy - 0.5f * h) * ih;
        o[2] = (cx + 0.5f * w) * iw;
        o[3] = (cy + 0.5f * h) * ih;
    }
}

// ------------- Kernel B: rank-by-count sort, grid=(4 q-chunks, NB) ---------
__global__ __launch_bounds__(256) void kB(
    const float* __restrict__ ws_max, const int* __restrict__ ws_lab,
    const float* __restrict__ out_sb, const float* __restrict__ out_ob,
    int* __restrict__ ws_ord,
    float4* __restrict__ sbox4, float4* __restrict__ obox4,
    float* __restrict__ sar, float* __restrict__ oar,
    int* __restrict__ slab)
{
    __shared__ float sc[NQ];
    int b = blockIdx.y, t = threadIdx.x;
    for (int i = t; i < NQ; i += 256) sc[i] = ws_max[b * NQ + i];
    __syncthreads();
    int q = blockIdx.x * 256 + t;
    if (q >= NQ) return;
    float sq = sc[q];
    int rank = 0;
    #pragma unroll 4
    for (int j = 0; j < NQ; ++j) {
        float sj = sc[j];
        rank += (sj > sq) || (sj == sq && j < q);
    }
    int src = b * NQ + q, dst = b * NQ + rank;
    ws_ord[dst] = q;
    float4 s4 = *reinterpret_cast<const float4*>(out_sb + (size_t)src * 4);
    float4 o4 = *reinterpret_cast<const float4*>(out_ob + (size_t)src * 4);
    sbox4[dst] = s4;
    obox4[dst] = o4;
    sar[dst] = (s4.z - s4.x + 1.0f) * (s4.w - s4.y + 1.0f);
    oar[dst] = (o4.z - o4.x + 1.0f) * (o4.w - o4.y + 1.0f);
    slab[dst] = ws_lab[src];
}

// ------- Kernel C: register-tiled 64x64 cand bitmask, one wave per tile ----
// Writes ONLY upper-triangle words (tj >= ti); kD never reads the rest.
__global__ __launch_bounds__(256) void kC(
    const float4* __restrict__ sbox4, const float4* __restrict__ obox4,
    const float* __restrict__ sar, const float* __restrict__ oar,
    const int* __restrict__ slab, u64* __restrict__ cand)
{
    int b = blockIdx.y;
    int base = b * NQ;
    int lane = threadIdx.x & 63, wv = threadIdx.x >> 6;
    int tl = blockIdx.x * 4 + wv;          // 0..119 upper-triangle tile id
    int ti = 0;
    while (tl >= NWORD - ti) { tl -= NWORD - ti; ++ti; }
    int tj = ti + tl;

    // lane j data (columns of the tile), registers only
    int j = tj * 64 + lane;
    int jc = min(j, NQ - 1);
    float4 sj = sbox4[base + jc];
    float4 oj = obox4[base + jc];
    float  saj = sar[base + jc];
    float  oaj = oar[base + jc];
    int    lj  = (j < NQ) ? slab[base + jc] : -1;

    // lane i data (rows of the tile), broadcast via readlane in the loop
    int il = ti * 64 + lane;
    int ic = min(il, NQ - 1);
    float4 siL = sbox4[base + ic];
    float4 oiL = obox4[base + ic];
    float  saiL = sar[base + ic];
    float  oaiL = oar[base + ic];
    int    liL  = slab[base + ic];

    u64 myword = 0ull;
    #pragma unroll
    for (int r = 0; r < 64; ++r) {
        int i = ti * 64 + r;
        if (i < NQ) {                      // wave-uniform guard (partial tile 14)
            int li = __shfl(liL, r);
            bool cl = (j > i) && (lj == li);   // invalid j has lj==-1 -> false
            u64 bal = 0ull;
            if (__any((int)cl)) {
                float six = __shfl(siL.x, r), siy = __shfl(siL.y, r);
                float siz = __shfl(siL.z, r), siw = __shfl(siL.w, r);
                float oix = __shfl(oiL.x, r), oiy = __shfl(oiL.y, r);
                float oiz = __shfl(oiL.z, r), oiw = __shfl(oiL.w, r);
                float sai = __shfl(saiL, r),  oai = __shfl(oaiL, r);
                float xx1 = fmaxf(six, sj.x), yy1 = fmaxf(siy, sj.y);
                float xx2 = fminf(siz, sj.z), yy2 = fminf(siw, sj.w);
                float w = fmaxf(0.0f, xx2 - xx1 + 1.0f);
                float h = fmaxf(0.0f, yy2 - yy1 + 1.0f);
                float iS = w * h;
                float uS = sai + saj - iS;
                xx1 = fmaxf(oix, oj.x); yy1 = fmaxf(oiy, oj.y);
                xx2 = fminf(oiz, oj.z); yy2 = fminf(oiw, oj.w);
                w = fmaxf(0.0f, xx2 - xx1 + 1.0f);
                h = fmaxf(0.0f, yy2 - yy1 + 1.0f);
                float iO = w * h;
                float uO = oai + oaj - iO;
                // iouS * sqrt(iouO) > 0.7  <=>  iS^2*iO > 0.49*uS^2*uO
                bool pred = cl && (iS * iS * iO > 0.49f * uS * uS * uO);
                bal = __ballot((int)pred);
            }
            if (lane == r) myword = bal;   // lane r keeps row i's word
        }
    }
    if (il < NQ) cand[(size_t)(base + il) * WSTRIDE + tj] = myword;
}

// ------- Kernel D: chunked greedy, SALU-scalar 64x64 resolution ------------
#define CHUNK 64
__global__ __launch_bounds__(256) void kD(
    const u64* __restrict__ cand, const int* __restrict__ ws_ord,
    float* __restrict__ out_keep)
{
    __shared__ u64  cl[2][CHUNK * LSTRIDE];   // padded rows: stride-17 u64
    __shared__ int  ord[NQ];
    __shared__ u64  keepw[NWORD];
    int b = blockIdx.x, t = threadIdx.x;
    int lane = t & 63, wv = t >> 6;
    const u64* src = cand + (size_t)b * NQ * WSTRIDE;

    for (int k = t; k < CHUNK * WSTRIDE; k += 256)
        cl[0][(k >> 4) * LSTRIDE + (k & 15)] = src[k];
    for (int k = t; k < NQ; k += 256) ord[k] = ws_ord[b * NQ + k];
    __syncthreads();

    const int nch = (NQ + CHUNK - 1) / CHUNK;   // 15 (last chunk: 4 rows)
    u64 remv = 0ull;    // lane l holds suppressed-mask word (l & 15)
    for (int ch = 0; ch < nch; ++ch) {
        // waves 1..3: prefetch next chunk
        if (wv > 0 && ch + 1 < nch) {
            int gbase = (ch + 1) * CHUNK * WSTRIDE;
            int cnt = min(CHUNK, NQ - (ch + 1) * CHUNK) * WSTRIDE;
            for (int k = t - 64; k < cnt; k += 192)
                cl[(ch + 1) & 1][(k >> 4) * LSTRIDE + (k & 15)] = src[gbase + k];
        }
        // wave 0: resolve this chunk
        if (wv == 0) {
            const u64* C = cl[ch & 1];
            int rows = min(CHUNK, NQ - ch * CHUNK);
            // incoming suppressed word -> SGPR via readlane (remv word ch is in lane ch)
            unsigned inc_lo = __builtin_amdgcn_readlane((unsigned)remv, ch);
            unsigned inc_hi = __builtin_amdgcn_readlane((unsigned)(remv >> 32), ch);
            u64 introw = (lane < rows) ? C[lane * LSTRIDE + ch] : 0ull;
            unsigned ilo = (unsigned)introw, ihi = (unsigned)(introw >> 32);
            // sequential 64-row resolution, all wave-uniform -> SALU chain
            u64 supp = ((u64)inc_hi << 32) | inc_lo;
            #pragma unroll
            for (int r = 0; r < CHUNK; ++r) {
                u64 rowr = ((u64)__builtin_amdgcn_readlane(ihi, r) << 32)
                         |  (u64)__builtin_amdgcn_readlane(ilo, r);
                supp |= ((supp >> r) & 1ull) ? 0ull : rowr;
            }
            u64 keep = ~supp;
            // apply kept rows' suppression to FUTURE words only (w > ch)
            int w = lane & 15, g = lane >> 4;
            bool wok = (w > ch) && (w < NWORD);
            u64 acc = 0ull;
            #pragma unroll
            for (int k = 0; k < 16; ++k) {
                int r = g * 16 + k;
                u64 c = C[r * LSTRIDE + w];     // unconditional, pipelined
                if (wok && r < rows && ((keep >> r) & 1ull)) acc |= c;
            }
            acc |= __shfl_xor(acc, 16);
            acc |= __shfl_xor(acc, 32);
            remv |= acc;
            if (lane == 0) keepw[ch] = keep;
        }
        __syncthreads();
    }
    for (int k = t; k < NQ; k += 256)
        out_keep[b * NQ + ord[k]] = ((keepw[k >> 6] >> (k & 63)) & 1ull) ? 1.0f : 0.0f;
}

extern "C" void kernel_launch(void* const* d_in, const int* in_sizes, int n_in,
                              void* d_out, int out_size, void* d_ws, size_t ws_size,
                              hipStream_t stream)
{
    const float* obj_logits   = (const float*)d_in[0];
    const float* verb_logits  = (const float*)d_in[1];
    const float* sub_boxes    = (const float*)d_in[2];
    const float* obj_boxes    = (const float*)d_in[3];
    const int*   target_sizes = (const int*)d_in[4];
    const float* cmat         = (const float*)d_in[5];

    float* out      = (float*)d_out;
    float* out_hoi  = out;
    float* out_lab  = out_hoi + (size_t)NBQ * NVERB;
    float* out_sb   = out_lab + NBQ;
    float* out_ob   = out_sb + (size_t)NBQ * 4;
    float* out_keep = out_ob + (size_t)NBQ * 4;

    // workspace layout (16B-aligned first)
    char* w = (char*)d_ws;
    float4* sbox4 = (float4*)w;                       w += (size_t)NBQ * 16;
    float4* obox4 = (float4*)w;                       w += (size_t)NBQ * 16;
    u64*    cand  = (u64*)w;                          w += (size_t)NBQ * WSTRIDE * 8;
    float*  ws_max = (float*)w;                       w += (size_t)NBQ * 4;
    float*  sar   = (float*)w;                        w += (size_t)NBQ * 4;
    float*  oar   = (float*)w;                        w += (size_t)NBQ * 4;
    int*    ws_lab = (int*)w;                         w += (size_t)NBQ * 4;
    int*    slab  = (int*)w;                          w += (size_t)NBQ * 4;
    int*    ws_ord = (int*)w;                         w += (size_t)NBQ * 4;
    float*  cmatT = (float*)w;                        w += (size_t)NCLS * NVERB * 4;

    k0<<<(NCLS * NVERB + 255) / 256, 256, 0, stream>>>(cmat, cmatT);
    kA<<<NBQ / 16, 256, 0, stream>>>(obj_logits, verb_logits, sub_boxes, obj_boxes,
                                     target_sizes, cmatT,
                                     out_hoi, out_lab, out_sb, out_ob, ws_max, ws_lab);
    kB<<<dim3(4, NB), 256, 0, stream>>>(ws_max, ws_lab, out_sb, out_ob, ws_ord,
                                        sbox4, obox4, sar, oar, slab);
    kC<<<dim3(30, NB), 256, 0, stream>>>(sbox4, obox4, sar, oar, slab, cand);
    kD<<<NB, 256, 0, stream>>>(cand, ws_ord, out_keep);
}

// Round 7
// 79.102 us; speedup vs baseline: 3.0281x; 1.7341x over previous
//
#include <hip/hip_runtime.h>

typedef unsigned long long u64;

#define NB 64
#define NQ 900
#define NCLS 81     // C+1
#define NLAB 81     // possible argmax labels 0..80
#define NVERB 117
#define NBQ (NB*NQ)
#define NWORD 15    // max chunks per group (ceil(900/64))

// -------- Kernel 0: transpose correct_mat -> cmatT[81][117], row 80 = 1 ----
__global__ __launch_bounds__(256) void k0(
    const float* __restrict__ cmat, float* __restrict__ cmatT)
{
    int idx = blockIdx.x * 256 + threadIdx.x;
    if (idx >= NCLS * NVERB) return;
    int c = idx / NVERB, v = idx - c * NVERB;
    cmatT[idx] = (c < NCLS - 1) ? cmat[v * (NCLS - 1) + c] : 1.0f;
}

// -------- Kernel A: 4 rows/wave, ballot-argmax, coalesced mask loads -------
__global__ __launch_bounds__(256) void kA(
    const float* __restrict__ obj_logits, const float* __restrict__ verb_logits,
    const float* __restrict__ sub_boxes, const float* __restrict__ obj_boxes,
    const int* __restrict__ target_sizes, const float* __restrict__ cmatT,
    float* __restrict__ out_hoi, float* __restrict__ out_lab,
    float* __restrict__ out_sb, float* __restrict__ out_ob,
    float* __restrict__ ws_max, int* __restrict__ ws_lab)
{
    int wp   = (blockIdx.x * blockDim.x + threadIdx.x) >> 6;
    int lane = threadIdx.x & 63;
    int w0 = wp * 4;                 // 4 rows; 900 % 4 == 0 -> never cross batch
    int b = w0 / NQ;

    // ---- argmax over 81 logits: max-butterfly + ballot index recovery ----
    float OS[4]; int MI[4];
    #pragma unroll
    for (int r = 0; r < 4; ++r) {
        const float* ol = obj_logits + (size_t)(w0 + r) * NCLS;
        float A  = ol[lane];
        float Bv = (lane < NCLS - 64) ? ol[64 + lane] : -3.4e38f;
        float m = fmaxf(A, Bv);
        #pragma unroll
        for (int off = 32; off; off >>= 1) m = fmaxf(m, __shfl_xor(m, off));
        u64 balA = __ballot((int)(A == m));
        u64 balB = __ballot((int)(lane < NCLS - 64 && Bv == m));
        MI[r] = balA ? (__ffsll(balA) - 1) : (63 + __ffsll(balB));
        OS[r] = 1.0f / (1.0f + __expf(-m));
    }

    // ---- verbs: sigmoid * obj_score * maskT (coalesced), row max ----
    float MX[4];
    #pragma unroll
    for (int r = 0; r < 4; ++r) {
        const float* vl  = verb_logits + (size_t)(w0 + r) * NVERB;
        float*       oh  = out_hoi     + (size_t)(w0 + r) * NVERB;
        const float* cmr = cmatT + MI[r] * NVERB;
        float sa = vl[lane];
        float ka = cmr[lane];
        float ha = OS[r] * ka / (1.0f + __expf(-sa));
        float hb = -1.0f;
        if (lane < NVERB - 64) {
            float sb = vl[64 + lane];
            float kb = cmr[64 + lane];
            hb = OS[r] * kb / (1.0f + __expf(-sb));
            oh[64 + lane] = hb;
        }
        oh[lane] = ha;
        float mx = fmaxf(ha, hb);
        #pragma unroll
        for (int off = 32; off; off >>= 1) mx = fmaxf(mx, __shfl_xor(mx, off));
        MX[r] = mx;
    }

    // ---- scalar per-row outputs (values are wave-uniform) ----
    if (lane < 4) {
        int   mi = (lane == 0) ? MI[0] : (lane == 1) ? MI[1] : (lane == 2) ? MI[2] : MI[3];
        float mx = (lane == 0) ? MX[0] : (lane == 1) ? MX[1] : (lane == 2) ? MX[2] : MX[3];
        out_lab[w0 + lane] = (float)mi;
        ws_lab[w0 + lane]  = mi;
        ws_max[w0 + lane]  = mx;
    }

    // ---- scaled xyxy boxes: lanes 0-7 = {4 rows} x {sub,obj} ----
    if (lane < 8) {
        int row = w0 + (lane >> 1);
        const float* bx = ((lane & 1) == 0 ? sub_boxes : obj_boxes) + (size_t)row * 4;
        float* o = ((lane & 1) == 0 ? out_sb : out_ob) + (size_t)row * 4;
        float cx = bx[0], cy = bx[1], w = bx[2], h = bx[3];
        float ih = (float)target_sizes[b * 2 + 0];
        float iw = (float)target_sizes[b * 2 + 1];
        o[0] = (cx - 0.5f * w) * iw;
        o[1] = (cy - 0.5f * h) * ih;
        o[2] = (cx + 0.5f * w) * iw;
        o[3] = (cy + 0.5f * h) * ih;
    }
}

// ------------- Kernel B: rank-by-count sort, grid=(4 q-chunks, NB) ---------
__global__ __launch_bounds__(256) void kB(
    const float* __restrict__ ws_max, const int* __restrict__ ws_lab,
    const float* __restrict__ out_sb, const float* __restrict__ out_ob,
    int* __restrict__ ws_ord,
    float4* __restrict__ sbox4, float4* __restrict__ obox4,
    float* __restrict__ sar, float* __restrict__ oar,
    int* __restrict__ slab)
{
    __shared__ float sc[NQ];
    int b = blockIdx.y, t = threadIdx.x;
    for (int i = t; i < NQ; i += 256) sc[i] = ws_max[b * NQ + i];
    __syncthreads();
    int q = blockIdx.x * 256 + t;
    if (q >= NQ) return;
    float sq = sc[q];
    int rank = 0;
    #pragma unroll 4
    for (int j = 0; j < NQ; ++j) {
        float sj = sc[j];
        rank += (sj > sq) || (sj == sq && j < q);
    }
    int src = b * NQ + q, dst = b * NQ + rank;
    ws_ord[dst] = q;
    float4 s4 = *reinterpret_cast<const float4*>(out_sb + (size_t)src * 4);
    float4 o4 = *reinterpret_cast<const float4*>(out_ob + (size_t)src * 4);
    sbox4[dst] = s4;
    obox4[dst] = o4;
    sar[dst] = (s4.z - s4.x + 1.0f) * (s4.w - s4.y + 1.0f);
    oar[dst] = (o4.z - o4.x + 1.0f) * (o4.w - o4.y + 1.0f);
    slab[dst] = ws_lab[src];
}

// ---------------- Kernel E: per-(batch,label) greedy NMS, one wave each ----
// Suppression graph is block-diagonal under labels (cand requires same label),
// so greedy NMS decomposes into independent per-label greedy chains in rank
// order. Group size g ~ Binomial(900, 1/81) ~ 11; chunked path handles any g.
__device__ __forceinline__ float bc(float x, int r) {
    return __uint_as_float(__builtin_amdgcn_readlane(__float_as_uint(x), r));
}

__device__ __forceinline__ bool iou_pred(
    const float4& sj, const float4& oj, float saj, float oaj,
    float six, float siy, float siz, float siw,
    float oix, float oiy, float oiz, float oiw, float sai, float oai)
{
    float xx1 = fmaxf(six, sj.x), yy1 = fmaxf(siy, sj.y);
    float xx2 = fminf(siz, sj.z), yy2 = fminf(siw, sj.w);
    float w = fmaxf(0.0f, xx2 - xx1 + 1.0f);
    float h = fmaxf(0.0f, yy2 - yy1 + 1.0f);
    float iS = w * h, uS = sai + saj - iS;
    xx1 = fmaxf(oix, oj.x); yy1 = fmaxf(oiy, oj.y);
    xx2 = fminf(oiz, oj.z); yy2 = fminf(oiw, oj.w);
    w = fmaxf(0.0f, xx2 - xx1 + 1.0f);
    h = fmaxf(0.0f, yy2 - yy1 + 1.0f);
    float iO = w * h, uO = oai + oaj - iO;
    // iouS * sqrt(iouO) > 0.7  <=>  iS^2*iO > 0.49*uS^2*uO  (all nonneg)
    return iS * iS * iO > 0.49f * uS * uS * uO;
}

__global__ __launch_bounds__(256) void kE(
    const float4* __restrict__ sbox4, const float4* __restrict__ obox4,
    const float* __restrict__ sar, const float* __restrict__ oar,
    const int* __restrict__ slab, const int* __restrict__ ws_ord,
    float* __restrict__ out_keep)
{
    __shared__ unsigned short mem[4][NQ];   // per-wave member rank lists
    __shared__ u64 keptm[4][NWORD];         // per-wave kept bits per chunk
    int b = blockIdx.y, base = b * NQ;
    int lane = threadIdx.x & 63, wv = threadIdx.x >> 6;
    int l = blockIdx.x * 4 + wv;
    if (l >= NLAB) return;

    // ---- collect members of label l in rank order (ballot-compaction) ----
    int g = 0;
    for (int k0 = 0; k0 < NQ; k0 += 64) {
        int k = k0 + lane;
        int lb = (k < NQ) ? slab[base + k] : -1;
        u64 bal = __ballot((int)(lb == l));
        if (lb == l) {
            int pos = g + __popcll(bal & (((u64)1 << lane) - 1));
            mem[wv][pos] = (unsigned short)k;
        }
        g += __popcll(bal);
    }

    int nch = (g + 63) >> 6;
    for (int c = 0; c < nch; ++c) {
        int rows = min(64, g - c * 64);
        bool vl = lane < rows;
        int rk = vl ? (int)mem[wv][c * 64 + lane] : 0;
        float4 sj = sbox4[base + rk];
        float4 oj = obox4[base + rk];
        float saj = sar[base + rk], oaj = oar[base + rk];

        // ---- cross-chunk: suppression by kept members of earlier chunks ----
        u64 pre = 0ull;
        for (int e = 0; e < c; ++e) {
            int rkE = (int)mem[wv][e * 64 + lane];   // chunk e is always full
            float4 sE = sbox4[base + rkE];
            float4 oE = obox4[base + rkE];
            float saE = sar[base + rkE], oaE = oar[base + rkE];
            u64 ke = keptm[wv][e];
            for (int r = 0; r < 64; ++r) {
                if ((ke >> r) & 1ull) {
                    bool p = vl && iou_pred(sj, oj, saj, oaj,
                        bc(sE.x, r), bc(sE.y, r), bc(sE.z, r), bc(sE.w, r),
                        bc(oE.x, r), bc(oE.y, r), bc(oE.z, r), bc(oE.w, r),
                        bc(saE, r), bc(oaE, r));
                    pre |= __ballot((int)p);
                }
            }
        }

        // ---- within-chunk cand words: lane r keeps row r's column word ----
        u64 myword = 0ull;
        for (int r = 0; r < rows; ++r) {
            bool p = vl && (lane > r) && iou_pred(sj, oj, saj, oaj,
                bc(sj.x, r), bc(sj.y, r), bc(sj.z, r), bc(sj.w, r),
                bc(oj.x, r), bc(oj.y, r), bc(oj.z, r), bc(oj.w, r),
                bc(saj, r), bc(oaj, r));
            u64 bal = __ballot((int)p);
            if (lane == r) myword = bal;
        }

        // ---- sequential resolution (SALU chain over uniform values) ----
        unsigned ilo = (unsigned)myword, ihi = (unsigned)(myword >> 32);
        u64 supp = pre;
        for (int r = 0; r < rows; ++r) {
            u64 rowr = ((u64)__builtin_amdgcn_readlane(ihi, r) << 32)
                     |  (u64)__builtin_amdgcn_readlane(ilo, r);
            supp |= ((supp >> r) & 1ull) ? 0ull : rowr;
        }
        u64 keep = ~supp;
        if (lane == 0)
            keptm[wv][c] = keep & ((rows == 64) ? ~0ull : (((u64)1 << rows) - 1));
        if (vl)
            out_keep[base + ws_ord[base + rk]] =
                ((keep >> lane) & 1ull) ? 1.0f : 0.0f;
    }
}

extern "C" void kernel_launch(void* const* d_in, const int* in_sizes, int n_in,
                              void* d_out, int out_size, void* d_ws, size_t ws_size,
                              hipStream_t stream)
{
    const float* obj_logits   = (const float*)d_in[0];
    const float* verb_logits  = (const float*)d_in[1];
    const float* sub_boxes    = (const float*)d_in[2];
    const float* obj_boxes    = (const float*)d_in[3];
    const int*   target_sizes = (const int*)d_in[4];
    const float* cmat         = (const float*)d_in[5];

    float* out      = (float*)d_out;
    float* out_hoi  = out;
    float* out_lab  = out_hoi + (size_t)NBQ * NVERB;
    float* out_sb   = out_lab + NBQ;
    float* out_ob   = out_sb + (size_t)NBQ * 4;
    float* out_keep = out_ob + (size_t)NBQ * 4;

    // workspace layout (16B-aligned first)
    char* w = (char*)d_ws;
    float4* sbox4 = (float4*)w;                       w += (size_t)NBQ * 16;
    float4* obox4 = (float4*)w;                       w += (size_t)NBQ * 16;
    float*  ws_max = (float*)w;                       w += (size_t)NBQ * 4;
    float*  sar   = (float*)w;                        w += (size_t)NBQ * 4;
    float*  oar   = (float*)w;                        w += (size_t)NBQ * 4;
    int*    ws_lab = (int*)w;                         w += (size_t)NBQ * 4;
    int*    slab  = (int*)w;                          w += (size_t)NBQ * 4;
    int*    ws_ord = (int*)w;                         w += (size_t)NBQ * 4;
    float*  cmatT = (float*)w;                        w += (size_t)NCLS * NVERB * 4;

    k0<<<(NCLS * NVERB + 255) / 256, 256, 0, stream>>>(cmat, cmatT);
    kA<<<NBQ / 16, 256, 0, stream>>>(obj_logits, verb_logits, sub_boxes, obj_boxes,
                                     target_sizes, cmatT,
                                     out_hoi, out_lab, out_sb, out_ob, ws_max, ws_lab);
    kB<<<dim3(4, NB), 256, 0, stream>>>(ws_max, ws_lab, out_sb, out_ob, ws_ord,
                                        sbox4, obox4, sar, oar, slab);
    kE<<<dim3((NLAB + 3) / 4, NB), 256, 0, stream>>>(sbox4, obox4, sar, oar,
                                                     slab, ws_ord, out_keep);
}